// Round 4
// baseline (372.209 us; speedup 1.0000x reference)
//
#include <hip/hip_runtime.h>
#include <stdint.h>

#define NN   2048
#define DD   128
#define DIN  256
#define ROWZ 75

typedef float f32x4 __attribute__((ext_vector_type(4)));
typedef short bf16x8 __attribute__((ext_vector_type(8)));
typedef unsigned int u32x4 __attribute__((ext_vector_type(4)));
typedef unsigned int u32x2 __attribute__((ext_vector_type(2)));

__device__ __forceinline__ unsigned short f2bf(float x){
  union { float f; unsigned int u; } v; v.f = x;
  unsigned int u = v.u;
  u += 0x7fffu + ((u >> 16) & 1u);   // RNE
  return (unsigned short)(u >> 16);
}
__device__ __forceinline__ float bf2f(unsigned short b){
  union { float f; unsigned int u; } v; v.u = ((unsigned int)b) << 16;
  return v.f;
}

// ---------------------------------------------------------------------------
// Kernel A: Wh = h @ W (fp32), row L2 norms.  (unchanged from R3)
// ---------------------------------------------------------------------------
__launch_bounds__(256, 2)
__global__ void wh_kernel(const float* __restrict__ h, const float* __restrict__ W,
                          unsigned short* __restrict__ whn, unsigned short* __restrict__ whT)
{
  __shared__ float hs[32][36];
  __shared__ float Ws[32][128];
  __shared__ float ssp[32][33];
  __shared__ float sinv[32];

  const int t  = threadIdx.x;
  const int r0 = blockIdx.x * 32;
  const int r4 = (t >> 5) * 4;
  const int d4 = (t & 31) * 4;

  float acc[4][4];
#pragma unroll
  for (int i = 0; i < 4; ++i)
#pragma unroll
    for (int j = 0; j < 4; ++j) acc[i][j] = 0.f;

  const int lrow = t >> 3;
  const int lkb  = (t & 7) * 4;

  for (int kt = 0; kt < 8; ++kt){
    __syncthreads();
    {
      const float* src = h + (size_t)(r0 + lrow) * DIN + kt * 32 + lkb;
      f32x4 a = *(const f32x4*)src;
#pragma unroll
      for (int e = 0; e < 4; ++e) hs[lkb + e][lrow] = a[e];
    }
    {
      const int k = t >> 3;
      const int d = (t & 7) * 16;
      const float* src = W + (size_t)(kt * 32 + k) * DD + d;
      float* dst = &Ws[k][d];
#pragma unroll
      for (int e = 0; e < 4; ++e) ((f32x4*)dst)[e] = ((const f32x4*)src)[e];
    }
    __syncthreads();
#pragma unroll
    for (int k = 0; k < 32; ++k){
      f32x4 w4 = *(const f32x4*)&Ws[k][d4];
      f32x4 ha = *(const f32x4*)&hs[k][r4];
#pragma unroll
      for (int i = 0; i < 4; ++i)
#pragma unroll
        for (int j = 0; j < 4; ++j)
          acc[i][j] += ha[i] * w4[j];
    }
  }

#pragma unroll
  for (int i = 0; i < 4; ++i){
    float s = acc[i][0]*acc[i][0] + acc[i][1]*acc[i][1]
            + acc[i][2]*acc[i][2] + acc[i][3]*acc[i][3];
    ssp[r4 + i][t & 31] = s;
  }
  __syncthreads();
  if (t < 32){
    float ss = 0.f;
#pragma unroll
    for (int c = 0; c < 32; ++c) ss += ssp[t][c];
    sinv[t] = 1.0f / fmaxf(sqrtf(ss), 1e-12f);
  }
  __syncthreads();

  const int bb = r0 >> 11;
  const int n0 = (r0 & 2047) + r4;

#pragma unroll
  for (int i = 0; i < 4; ++i){
    const float inv = sinv[r4 + i];
    unsigned int lo = (unsigned int)f2bf(acc[i][0]*inv) | ((unsigned int)f2bf(acc[i][1]*inv) << 16);
    unsigned int hi = (unsigned int)f2bf(acc[i][2]*inv) | ((unsigned int)f2bf(acc[i][3]*inv) << 16);
    u32x2 pk = { lo, hi };
    *(u32x2*)(whn + (size_t)(r0 + r4 + i) * DD + d4) = pk;
  }
#pragma unroll
  for (int j = 0; j < 4; ++j){
    u32x2 pk;
#pragma unroll
    for (int e = 0; e < 2; ++e)
      pk[e] = (unsigned int)f2bf(acc[2*e][j]) | ((unsigned int)f2bf(acc[2*e + 1][j]) << 16);
    *(u32x2*)(whT + ((size_t)(bb * DD + d4 + j)) * NN + n0) = pk;
  }
}

// ---------------------------------------------------------------------------
// Kernel B (R4): BARRIER-FREE fused attention.
// One wave = 16 q-rows x full m-sweep (64 iters of m=32). P is wave-local
// (LDS round-trip, no barrier); l and O finish in-wave. V fragments loaded
// directly from global whT (no Vt tile, no DMA, no __syncthreads in kernel).
// FIFO-correct pipeline: issue [kf(i+1), vf(i+1), adj(i+2)] then compute i —
// waiting on kf(i) (issued a full iter ago) never drains younger adj loads.
// blockIdx&7 = batch -> each XCD's L2 caches exactly its batch (1 MB).
// ---------------------------------------------------------------------------
__launch_bounds__(128, 2)
__global__ void attn_kernel(const unsigned short* __restrict__ whn,
                            const unsigned short* __restrict__ whT,
                            const int* __restrict__ adj,
                            float* __restrict__ out)
{
  __shared__ unsigned short Pbuf[2][16 * 40];   // per-wave P, stride 40 (16B-aligned rows)

  const int t    = threadIdx.x;
  const int w    = t >> 6;
  const int l    = t & 63;
  const int quad = l >> 4;
  const int l16  = l & 15;
  const int b    = blockIdx.x & 7;              // batch -> XCD pinning
  const int qt   = blockIdx.x >> 3;             // 0..63
  const int q0   = qt * 32 + w * 16;            // wave's q-row base

  const unsigned short* whn_b = whn + (size_t)b * NN * DD;
  const unsigned short* whT_b = whT + (size_t)b * DD * NN;
  const int*            adj_b = adj + (size_t)b * NN * NN;

  // persistent Q fragments (A-layout: row=l16, k=quad*8+j)
  bf16x8 qf[4];
#pragma unroll
  for (int kc = 0; kc < 4; ++kc)
    qf[kc] = *(const bf16x8*)(whn_b + (size_t)(q0 + l16) * DD + kc*32 + quad*8);

  f32x4 oacc[8];
  float lacc[4];
#pragma unroll
  for (int dt = 0; dt < 8; ++dt) oacc[dt] = (f32x4){0.f, 0.f, 0.f, 0.f};
#pragma unroll
  for (int r = 0; r < 4; ++r) lacc[r] = 0.f;

  const int arow = q0 + quad*4;                 // +r = this lane's adj rows

  // ---- prologue: adj(0), adj(1), kf(0), vf(0) ----
  int av0[2][4], av1[2][4];
#pragma unroll
  for (int f = 0; f < 2; ++f)
#pragma unroll
    for (int r = 0; r < 4; ++r){
      av0[f][r] = adj_b[(size_t)(arow + r) * NN +  0 + f*16 + l16];
      av1[f][r] = adj_b[(size_t)(arow + r) * NN + 32 + f*16 + l16];
    }
  bf16x8 kf0[2][4], vf0[8];
#pragma unroll
  for (int f = 0; f < 2; ++f)
#pragma unroll
    for (int kc = 0; kc < 4; ++kc)
      kf0[f][kc] = *(const bf16x8*)(whn_b + (size_t)(f*16 + l16) * DD + kc*32 + quad*8);
#pragma unroll
  for (int dt = 0; dt < 8; ++dt)
    vf0[dt] = *(const bf16x8*)(whT_b + (size_t)(dt*16 + l16) * NN + quad*8);

  unsigned short* const Pw = &Pbuf[w][0];

  for (int it = 0; it < 64; ++it){
    const int m0 = it * 32;
    const int mn = (m0 + 32) & 2047;            // next m-chunk (wraps to dummy at end)
    const int ma = (m0 + 64) & 2047;            // adj prefetch, distance 2

    // ---- issue next-iteration loads FIRST (FIFO: kf -> vf -> adj) ----
    bf16x8 kfn[2][4], vfn[8];
    int avn[2][4];
#pragma unroll
    for (int f = 0; f < 2; ++f)
#pragma unroll
      for (int kc = 0; kc < 4; ++kc)
        kfn[f][kc] = *(const bf16x8*)(whn_b + (size_t)(mn + f*16 + l16) * DD + kc*32 + quad*8);
#pragma unroll
    for (int dt = 0; dt < 8; ++dt)
      vfn[dt] = *(const bf16x8*)(whT_b + (size_t)(dt*16 + l16) * NN + mn + quad*8);
#pragma unroll
    for (int f = 0; f < 2; ++f)
#pragma unroll
      for (int r = 0; r < 4; ++r)
        avn[f][r] = adj_b[(size_t)(arow + r) * NN + ma + f*16 + l16];

    // ---- QK + mask + exp -> P (uses kf0/av0, loaded >=1 iter ago) ----
#pragma unroll
    for (int f = 0; f < 2; ++f){
      f32x4 sc = (f32x4){0.f, 0.f, 0.f, 0.f};
#pragma unroll
      for (int kc = 0; kc < 4; ++kc)
        sc = __builtin_amdgcn_mfma_f32_16x16x32_bf16(qf[kc], kf0[f][kc], sc, 0, 0, 0);
#pragma unroll
      for (int r = 0; r < 4; ++r){
        const int qrow = arow + r;
        float sv = (qrow < ROWZ) ? 0.f : sc[r];           // row-zeroing bug emulation
        float p32 = (av0[f][r] > 0) ? __expf(sv) : 0.f;
        unsigned short pb = f2bf(p32);
        lacc[r] += bf2f(pb);
        Pw[(quad*4 + r) * 40 + f*16 + l16] = pb;          // C-layout -> LDS
      }
    }

    // ---- PV: O += P[16x32] * V[32x128] (wave-local P; lgkmcnt only) ----
    {
      bf16x8 pf = *(const bf16x8*)&Pw[l16 * 40 + quad*8]; // A-layout read
#pragma unroll
      for (int dt = 0; dt < 8; ++dt)
        oacc[dt] = __builtin_amdgcn_mfma_f32_16x16x32_bf16(pf, vf0[dt], oacc[dt], 0, 0, 0);
    }

    // ---- rotate pipeline registers ----
#pragma unroll
    for (int f = 0; f < 2; ++f){
#pragma unroll
      for (int kc = 0; kc < 4; ++kc) kf0[f][kc] = kfn[f][kc];
#pragma unroll
      for (int r = 0; r < 4; ++r){ av0[f][r] = av1[f][r]; av1[f][r] = avn[f][r]; }
    }
#pragma unroll
    for (int dt = 0; dt < 8; ++dt) vf0[dt] = vfn[dt];
  }

  // ---- epilogue: in-wave l reduction (16 lanes per quad share rows) ----
  float linv[4];
#pragma unroll
  for (int r = 0; r < 4; ++r){
    float s = lacc[r];
    s += __shfl_xor(s, 1);
    s += __shfl_xor(s, 2);
    s += __shfl_xor(s, 4);
    s += __shfl_xor(s, 8);
    linv[r] = 1.0f / s;
  }

  // ---- scale, ELU, store (C-layout: row=quad*4+r, col=dt*16+l16) ----
#pragma unroll
  for (int dt = 0; dt < 8; ++dt)
#pragma unroll
    for (int r = 0; r < 4; ++r){
      float v = oacc[dt][r] * linv[r];
      v = (v > 0.f) ? v : expm1f(v);   // ELU (alpha=1)
      out[((size_t)b * NN + q0 + quad*4 + r) * DD + dt*16 + l16] = v;
    }
}

extern "C" void kernel_launch(void* const* d_in, const int* in_sizes, int n_in,
                              void* d_out, int out_size, void* d_ws, size_t ws_size,
                              hipStream_t stream)
{
  const float* h       = (const float*)d_in[0];
  // d_in[1] = adj  (unused by the reference)
  const int*   adj_eye = (const int*)d_in[2];
  const float* W       = (const float*)d_in[3];
  float*       out     = (float*)d_out;

  unsigned short* whn = (unsigned short*)d_ws;                    // 16384*128 bf16 = 4 MB
  unsigned short* whT = whn + (size_t)16384 * 128;                // 8*128*2048 bf16 = 4 MB

  wh_kernel<<<512, 256, 0, stream>>>(h, W, whn, whT);
  attn_kernel<<<512, 128, 0, stream>>>(whn, whT, adj_eye, out);
}

// Round 7
// 324.264 us; speedup vs baseline: 1.1479x; 1.1479x over previous
//
#include <hip/hip_runtime.h>
#include <stdint.h>

#define NN   2048
#define DD   128
#define DIN  256
#define ROWZ 75

typedef float f32x4 __attribute__((ext_vector_type(4)));
typedef short bf16x8 __attribute__((ext_vector_type(8)));
typedef unsigned int u32x4 __attribute__((ext_vector_type(4)));
typedef unsigned int u32x2 __attribute__((ext_vector_type(2)));

__device__ __forceinline__ unsigned short f2bf(float x){
  union { float f; unsigned int u; } v; v.f = x;
  unsigned int u = v.u;
  u += 0x7fffu + ((u >> 16) & 1u);   // RNE
  return (unsigned short)(u >> 16);
}
__device__ __forceinline__ float bf2f(unsigned short b){
  union { float f; unsigned int u; } v; v.u = ((unsigned int)b) << 16;
  return v.f;
}

// ---------------------------------------------------------------------------
// Kernel A: Wh = h @ W (fp32), row L2 norms.  (unchanged — passed 3x)
// ---------------------------------------------------------------------------
__launch_bounds__(256, 2)
__global__ void wh_kernel(const float* __restrict__ h, const float* __restrict__ W,
                          unsigned short* __restrict__ whn, unsigned short* __restrict__ whT)
{
  __shared__ float hs[32][36];
  __shared__ float Ws[32][128];
  __shared__ float ssp[32][33];
  __shared__ float sinv[32];

  const int t  = threadIdx.x;
  const int r0 = blockIdx.x * 32;
  const int r4 = (t >> 5) * 4;
  const int d4 = (t & 31) * 4;

  float acc[4][4];
#pragma unroll
  for (int i = 0; i < 4; ++i)
#pragma unroll
    for (int j = 0; j < 4; ++j) acc[i][j] = 0.f;

  const int lrow = t >> 3;
  const int lkb  = (t & 7) * 4;

  for (int kt = 0; kt < 8; ++kt){
    __syncthreads();
    {
      const float* src = h + (size_t)(r0 + lrow) * DIN + kt * 32 + lkb;
      f32x4 a = *(const f32x4*)src;
#pragma unroll
      for (int e = 0; e < 4; ++e) hs[lkb + e][lrow] = a[e];
    }
    {
      const int k = t >> 3;
      const int d = (t & 7) * 16;
      const float* src = W + (size_t)(kt * 32 + k) * DD + d;
      float* dst = &Ws[k][d];
#pragma unroll
      for (int e = 0; e < 4; ++e) ((f32x4*)dst)[e] = ((const f32x4*)src)[e];
    }
    __syncthreads();
#pragma unroll
    for (int k = 0; k < 32; ++k){
      f32x4 w4 = *(const f32x4*)&Ws[k][d4];
      f32x4 ha = *(const f32x4*)&hs[k][r4];
#pragma unroll
      for (int i = 0; i < 4; ++i)
#pragma unroll
        for (int j = 0; j < 4; ++j)
          acc[i][j] += ha[i] * w4[j];
    }
  }

#pragma unroll
  for (int i = 0; i < 4; ++i){
    float s = acc[i][0]*acc[i][0] + acc[i][1]*acc[i][1]
            + acc[i][2]*acc[i][2] + acc[i][3]*acc[i][3];
    ssp[r4 + i][t & 31] = s;
  }
  __syncthreads();
  if (t < 32){
    float ss = 0.f;
#pragma unroll
    for (int c = 0; c < 32; ++c) ss += ssp[t][c];
    sinv[t] = 1.0f / fmaxf(sqrtf(ss), 1e-12f);
  }
  __syncthreads();

  const int bb = r0 >> 11;
  const int n0 = (r0 & 2047) + r4;

#pragma unroll
  for (int i = 0; i < 4; ++i){
    const float inv = sinv[r4 + i];
    unsigned int lo = (unsigned int)f2bf(acc[i][0]*inv) | ((unsigned int)f2bf(acc[i][1]*inv) << 16);
    unsigned int hi = (unsigned int)f2bf(acc[i][2]*inv) | ((unsigned int)f2bf(acc[i][3]*inv) << 16);
    u32x2 pk = { lo, hi };
    *(u32x2*)(whn + (size_t)(r0 + r4 + i) * DD + d4) = pk;
  }
#pragma unroll
  for (int j = 0; j < 4; ++j){
    u32x2 pk;
#pragma unroll
    for (int e = 0; e < 2; ++e)
      pk[e] = (unsigned int)f2bf(acc[2*e][j]) | ((unsigned int)f2bf(acc[2*e + 1][j]) << 16);
    *(u32x2*)(whT + ((size_t)(bb * DD + d4 + j)) * NN + n0) = pk;
  }
}

// ---------------------------------------------------------------------------
// Kernel B (R7): R3's proven barrier structure; adj read ONCE per block in a
// streaming ballot-pack prologue -> 8.5 KB LDS mask. The m-loop has zero adj
// dependence (the R5 theory) with no extra workspace and no input writes.
// LDS: Vt 32K + Pbuf 10K + Ms 8.5K + linv 128B = 51.8 KB (2 blocks/CU).
// ---------------------------------------------------------------------------
__launch_bounds__(256, 2)
__global__ void attn_kernel(const unsigned short* __restrict__ whn,
                            const unsigned short* __restrict__ whT,
                            const int* __restrict__ adj,
                            float* __restrict__ out)
{
  __shared__ unsigned short Vt[128 * 128];      // 32 KB
  __shared__ unsigned short Pbuf[4][32 * 40];   // 10 KB
  __shared__ unsigned int   Ms[32 * 68];        // 8.5 KB, stride 68
  __shared__ float linv_s[32];

  const int t    = threadIdx.x;
  const int w    = t >> 6;
  const int l    = t & 63;
  const int quad = l >> 4;
  const int l16  = l & 15;
  const int b    = blockIdx.x >> 6;
  const int qbase = (blockIdx.x & 63) * 32;

  const unsigned short* whn_b = whn + (size_t)b * NN * DD;
  const unsigned short* whT_b = whT + (size_t)b * DD * NN;
  const int*            adj_b = adj + (size_t)b * NN * NN;

  // ---- prologue: ballot-pack this block's 32 adj rows into Ms ----
  // Wave w owns q-rows [qbase+w*8, +8). Per c-iter: 8 independent dword
  // loads/lane (256B/row coalesced) -> 8 ballots -> 2 uint stores (l<2).
  // Ballot bit l <-> column c*64+l; Ms word u covers columns u*32..u*32+31.
  {
    const int rbase = qbase + w * 8;
    for (int c = 0; c < 32; ++c){
      int a[8];
#pragma unroll
      for (int j = 0; j < 8; ++j)
        a[j] = adj_b[(size_t)(rbase + j) * NN + c*64 + l];
#pragma unroll
      for (int j = 0; j < 8; ++j){
        unsigned long long bb = __ballot(a[j] > 0);
        if (l < 2){
          unsigned int val = (l & 1) ? (unsigned int)(bb >> 32) : (unsigned int)bb;
          Ms[(w*8 + j) * 68 + c*2 + l] = val;
        }
      }
    }
  }

  // Q fragments (A-layout: row = lane&15, k = quad*8 + j), held all loop
  bf16x8 qf[2][4];
#pragma unroll
  for (int s = 0; s < 2; ++s)
#pragma unroll
    for (int kc = 0; kc < 4; ++kc)
      qf[s][kc] = *(const bf16x8*)(whn_b + (size_t)(qbase + s*16 + l16) * DD + kc*32 + quad*8);

  f32x4 oacc[2][8];
  float lacc[2][4];
#pragma unroll
  for (int s = 0; s < 2; ++s){
#pragma unroll
    for (int dt = 0; dt < 8; ++dt) oacc[s][dt] = (f32x4){0.f, 0.f, 0.f, 0.f};
#pragma unroll
    for (int r = 0; r < 4; ++r) lacc[s][r] = 0.f;
  }

  unsigned short* const Pw = &Pbuf[w][0];

  for (int it = 0; it < 16; ++it){
    const int m0 = it * 128;
    __syncthreads();   // prev Vt reads done; (it=0: Ms prologue visible)

    // ---- stage V^T tile via async global->LDS (16B/lane, 4 d-rows/instr) ----
#pragma unroll
    for (int ii = 0; ii < 8; ++ii){
      const int d   = w*32 + ii*4 + quad;
      const int gsw = l16 ^ (d & 7);               // xor granule swizzle
      const unsigned short* src = whT_b + (size_t)d * NN + m0 + gsw * 8;
      __builtin_amdgcn_global_load_lds(
          (const __attribute__((address_space(1))) void*)src,
          (__attribute__((address_space(3))) void*)&Vt[(w*32 + ii*4) * 128],
          16, 0, 0);
    }

    // ---- kf fragments for both f, batched ----
    bf16x8 kf[2][4];
#pragma unroll
    for (int f = 0; f < 2; ++f)
#pragma unroll
      for (int kc = 0; kc < 4; ++kc)
        kf[f][kc] = *(const bf16x8*)(whn_b + (size_t)(m0 + w*32 + f*16 + l16) * DD + kc*32 + quad*8);

    // ---- QK MFMAs ----
    f32x4 sc[2][2];
#pragma unroll
    for (int f = 0; f < 2; ++f)
#pragma unroll
      for (int s = 0; s < 2; ++s){
        f32x4 a = (f32x4){0.f, 0.f, 0.f, 0.f};
#pragma unroll
        for (int kc = 0; kc < 4; ++kc)
          a = __builtin_amdgcn_mfma_f32_16x16x32_bf16(qf[s][kc], kf[f][kc], a, 0, 0, 0);
        sc[f][s] = a;
      }

    // ---- mask (LDS bits) + row-zero + exp -> P ----
    const int uidx = (m0 >> 5) + w;   // wave-uniform uint index into mask rows
#pragma unroll
    for (int s = 0; s < 2; ++s)
#pragma unroll
      for (int r = 0; r < 4; ++r){
        const unsigned int mv = Ms[(s*16 + quad*4 + r) * 68 + uidx];
        const int qrow = qbase + s*16 + quad*4 + r;
#pragma unroll
        for (int f = 0; f < 2; ++f){
          float sv  = (qrow < ROWZ) ? 0.f : sc[f][s][r];      // row-zeroing bug emulation
          float p32 = ((mv >> (f*16 + l16)) & 1u) ? __expf(sv) : 0.f;
          unsigned short pb = f2bf(p32);
          lacc[s][r] += bf2f(pb);
          Pw[(s*16 + quad*4 + r) * 40 + f*16 + l16] = pb;     // C-layout -> LDS
        }
      }
    __syncthreads();   // drains vmcnt: Vt ready; P visible

    // ---- PV: out += P[16x32] * V[32x128] per q-subtile ----
#pragma unroll
    for (int s = 0; s < 2; ++s){
      bf16x8 pfr = *(const bf16x8*)&Pw[(s*16 + l16) * 40 + quad*8];  // A-layout read
#pragma unroll
      for (int dt = 0; dt < 8; ++dt){
        const int d  = dt*16 + l16;
        const int gg = (w*4 + quad) ^ (d & 7);
        bf16x8 vf = *(const bf16x8*)&Vt[d * 128 + gg * 8];
        oacc[s][dt] = __builtin_amdgcn_mfma_f32_16x16x32_bf16(pfr, vf, oacc[s][dt], 0, 0, 0);
      }
    }
  }

  // ---- l reduction (reuse own wave's Pbuf region as float scratch) ----
  {
    float* lredw = (float*)Pw;
#pragma unroll
    for (int s = 0; s < 2; ++s)
#pragma unroll
      for (int r = 0; r < 4; ++r)
        lredw[(s*16 + quad*4 + r) * 16 + l16] = lacc[s][r];
  }
  __syncthreads();
  if (t < 32){
    float sum = 0.f;
    for (int ww = 0; ww < 4; ++ww){
      const float* lr = (const float*)&Pbuf[ww][0];
#pragma unroll
      for (int c = 0; c < 16; ++c) sum += lr[t * 16 + c];
    }
    linv_s[t] = 1.0f / sum;
  }

  // ---- output reduction across waves (reuse Vt as 32KB float scratch) ----
  float* const ored = (float*)&Vt[0];
  for (int s = 0; s < 2; ++s){
    __syncthreads();
#pragma unroll
    for (int dt = 0; dt < 8; ++dt)
#pragma unroll
      for (int r = 0; r < 4; ++r)
        ored[w*2048 + (quad*4 + r)*128 + dt*16 + l16] = oacc[s][dt][r];
    __syncthreads();
#pragma unroll
    for (int j = 0; j < 8; ++j){
      const int o  = j*256 + t;
      const int ql = o >> 7, d = o & 127;
      float v = ored[ql*128 + d] + ored[2048 + ql*128 + d]
              + ored[4096 + ql*128 + d] + ored[6144 + ql*128 + d];
      v *= linv_s[s*16 + ql];
      v = (v > 0.f) ? v : expm1f(v);   // ELU (alpha=1)
      out[(size_t)(b*NN + qbase + s*16 + ql) * DD + d] = v;
    }
  }
}

extern "C" void kernel_launch(void* const* d_in, const int* in_sizes, int n_in,
                              void* d_out, int out_size, void* d_ws, size_t ws_size,
                              hipStream_t stream)
{
  const float* h       = (const float*)d_in[0];
  // d_in[1] = adj (unused by the reference; NOT touched)
  const int*   adj_eye = (const int*)d_in[2];
  const float* W       = (const float*)d_in[3];
  float*       out     = (float*)d_out;

  unsigned short* whn  = (unsigned short*)d_ws;                   // 4 MB
  unsigned short* whT  = whn + (size_t)16384 * 128;               // 4 MB (ws total: 8 MB, proven R2-R4)

  wh_kernel<<<512, 256, 0, stream>>>(h, W, whn, whT);
  attn_kernel<<<512, 256, 0, stream>>>(whn, whT, adj_eye, out);
}